// Round 1
// baseline (14995.102 us; speedup 1.0000x reference)
//
#include <hip/hip_runtime.h>
#include <hip/hip_bf16.h>
#include <math.h>

#define QLEN 1024
#define MLEN 1024
#define BSZ 4
#define KLEN 2048
#define NH 16
#define DH 64
#define DM 1024
#define DI 4096
#define NHD 1024
#define LN_EPS 1e-5f

// ---------------- workspace layout (floats) ----------------
// cat       @ 0          :  8,388,608   (KLEN*BSZ*DM)  [reused as ff_hidden later]
// w_heads   @ 8,388,608  : 25,165,824   (KLEN*BSZ*3*NHD)
// r_head_k  @ 33,554,432 :  2,097,152   (KLEN*NHD)
// attn_vec  @ 35,651,584 :  4,194,304   (QLEN*BSZ*NHD)
// tmp       @ 39,845,888 :  4,194,304   (QLEN*BSZ*DM)
// ln1_out   @ 44,040,192 :  4,194,304
// total 48,234,496 floats = 192,937,984 bytes
static const size_t OFF_CAT = 0;
static const size_t OFF_WH  = 8388608;
static const size_t OFF_RHK = 33554432;
static const size_t OFF_AV  = 35651584;
static const size_t OFF_TMP = 39845888;
static const size_t OFF_LN1 = 44040192;
static const size_t OFF_FFH = 0; // ff hidden reuses cat/w_heads region (dead by then)

// ---------------- generic 64x64 tiled fp32 GEMM ----------------
// C[M,N] = A[M,K] @ B[K,N] (+bias) (+relu). All dims multiples of 64/16.
// flags: 1 = add bias, 2 = relu
__global__ __launch_bounds__(256) void gemm64(const float* __restrict__ A,
                                              const float* __restrict__ B,
                                              const float* __restrict__ bias,
                                              float* __restrict__ C,
                                              int M, int N, int K, int flags) {
    __shared__ float As[64][17];
    __shared__ float Bs[16][65];
    int t = threadIdx.x;
    int col0 = blockIdx.x * 64;
    int row0 = blockIdx.y * 64;
    int tx = t % 16, ty = t / 16;

    int la_row = t >> 2;          // 0..63
    int la_col = (t & 3) * 4;     // 0,4,8,12
    int lb_row = t >> 4;          // 0..15
    int lb_col = (t & 15) * 4;    // 0..60

    float acc[4][4] = {};

    for (int k0 = 0; k0 < K; k0 += 16) {
        float4 av = *(const float4*)&A[(size_t)(row0 + la_row) * K + k0 + la_col];
        As[la_row][la_col + 0] = av.x;
        As[la_row][la_col + 1] = av.y;
        As[la_row][la_col + 2] = av.z;
        As[la_row][la_col + 3] = av.w;
        float4 bv = *(const float4*)&B[(size_t)(k0 + lb_row) * N + col0 + lb_col];
        Bs[lb_row][lb_col + 0] = bv.x;
        Bs[lb_row][lb_col + 1] = bv.y;
        Bs[lb_row][lb_col + 2] = bv.z;
        Bs[lb_row][lb_col + 3] = bv.w;
        __syncthreads();
#pragma unroll
        for (int kk = 0; kk < 16; ++kk) {
            float a0 = As[ty * 4 + 0][kk];
            float a1 = As[ty * 4 + 1][kk];
            float a2 = As[ty * 4 + 2][kk];
            float a3 = As[ty * 4 + 3][kk];
            float b0 = Bs[kk][tx * 4 + 0];
            float b1 = Bs[kk][tx * 4 + 1];
            float b2 = Bs[kk][tx * 4 + 2];
            float b3 = Bs[kk][tx * 4 + 3];
            acc[0][0] += a0 * b0; acc[0][1] += a0 * b1; acc[0][2] += a0 * b2; acc[0][3] += a0 * b3;
            acc[1][0] += a1 * b0; acc[1][1] += a1 * b1; acc[1][2] += a1 * b2; acc[1][3] += a1 * b3;
            acc[2][0] += a2 * b0; acc[2][1] += a2 * b1; acc[2][2] += a2 * b2; acc[2][3] += a2 * b3;
            acc[3][0] += a3 * b0; acc[3][1] += a3 * b1; acc[3][2] += a3 * b2; acc[3][3] += a3 * b3;
        }
        __syncthreads();
    }
#pragma unroll
    for (int i = 0; i < 4; ++i) {
#pragma unroll
        for (int j = 0; j < 4; ++j) {
            int r = row0 + ty * 4 + i;
            int c = col0 + tx * 4 + j;
            float v = acc[i][j];
            if (flags & 1) v += bias[c];
            if (flags & 2) v = fmaxf(v, 0.0f);
            C[(size_t)r * N + c] = v;
        }
    }
}

// ---------------- attention: one block per (query i, batch b, head n) ----------------
// w_heads rows: pos*BSZ + b, cols 3072 = [q | k | v], each col block n*64+d.
// q for query i is at pos MLEN+i. BD uses r_head_k[j + QLEN-1-i] (rel_shift resolved).
__global__ __launch_bounds__(256) void attn_kernel(const float* __restrict__ w_heads,
                                                   const float* __restrict__ r_head_k,
                                                   const float* __restrict__ r_w_bias,
                                                   const float* __restrict__ r_r_bias,
                                                   float* __restrict__ attn_vec) {
    const int i = blockIdx.x;
    const int bn = blockIdx.y;
    const int b = bn / NH;
    const int n = bn % NH;
    const int t = threadIdx.x;
    const float scale = 0.125f; // 1/sqrt(64)

    __shared__ float qac[DH];
    __shared__ float qbd[DH];
    __shared__ float p[KLEN];
    __shared__ float red[256];

    if (t < DH) {
        float qv = w_heads[((size_t)(MLEN + i) * BSZ + b) * 3072 + n * DH + t];
        qac[t] = qv + r_w_bias[n * DH + t];
        qbd[t] = qv + r_r_bias[n * DH + t];
    }
    __syncthreads();

    const int jmax = i + MLEN; // inclusive
    float lmax = -INFINITY;
    for (int j = t; j < KLEN; j += 256) {
        float s;
        if (j <= jmax) {
            const float* krow = &w_heads[((size_t)j * BSZ + b) * 3072 + NHD + n * DH];
            const float* rrow = &r_head_k[(size_t)(j + QLEN - 1 - i) * NHD + n * DH];
            float ac = 0.f, bd = 0.f;
#pragma unroll
            for (int d = 0; d < DH; ++d) {
                ac += qac[d] * krow[d];
                bd += qbd[d] * rrow[d];
            }
            s = (ac + bd) * scale;
        } else {
            s = -INFINITY;
        }
        p[j] = s;
        lmax = fmaxf(lmax, s);
    }
    red[t] = lmax;
    __syncthreads();
    for (int off = 128; off > 0; off >>= 1) {
        if (t < off) red[t] = fmaxf(red[t], red[t + off]);
        __syncthreads();
    }
    const float m = red[0];
    __syncthreads();

    float lsum = 0.f;
    for (int j = t; j < KLEN; j += 256) {
        float e = expf(p[j] - m); // -inf -> 0
        p[j] = e;
        lsum += e;
    }
    red[t] = lsum;
    __syncthreads();
    for (int off = 128; off > 0; off >>= 1) {
        if (t < off) red[t] += red[t + off];
        __syncthreads();
    }
    const float rsum = 1.0f / red[0];
    __syncthreads();

    // PV: 4 partial sums per output dim d
    const int d = t & 63;
    const int part = t >> 6;
    float acc = 0.f;
    for (int j = part; j <= jmax; j += 4) {
        acc += p[j] * w_heads[((size_t)j * BSZ + b) * 3072 + 2 * NHD + n * DH + d];
    }
    red[t] = acc;
    __syncthreads();
    if (part == 0) {
        float v = red[d] + red[64 + d] + red[128 + d] + red[192 + d];
        attn_vec[((size_t)i * BSZ + b) * NHD + n * DH + d] = v * rsum;
    }
}

// ---------------- residual add + layernorm, one block per row of 1024 ----------------
__global__ __launch_bounds__(256) void add_ln_kernel(const float* __restrict__ a,
                                                     const float* __restrict__ b,
                                                     const float* __restrict__ w,
                                                     const float* __restrict__ bias,
                                                     float* __restrict__ out) {
    const int row = blockIdx.x;
    const int t = threadIdx.x;
    __shared__ float xs[DM];
    __shared__ float red[256];

    const float* ar = a + (size_t)row * DM;
    const float* br = b + (size_t)row * DM;

    float lsum = 0.f;
#pragma unroll
    for (int c = t; c < DM; c += 256) {
        float v = ar[c] + br[c];
        xs[c] = v;
        lsum += v;
    }
    red[t] = lsum;
    __syncthreads();
    for (int off = 128; off > 0; off >>= 1) {
        if (t < off) red[t] += red[t + off];
        __syncthreads();
    }
    const float mu = red[0] * (1.0f / DM);
    __syncthreads();

    float lvar = 0.f;
#pragma unroll
    for (int c = t; c < DM; c += 256) {
        float dv = xs[c] - mu;
        lvar += dv * dv;
    }
    red[t] = lvar;
    __syncthreads();
    for (int off = 128; off > 0; off >>= 1) {
        if (t < off) red[t] += red[t + off];
        __syncthreads();
    }
    const float rstd = rsqrtf(red[0] * (1.0f / DM) + LN_EPS);
    __syncthreads();

    float* orow = out + (size_t)row * DM;
#pragma unroll
    for (int c = t; c < DM; c += 256) {
        orow[c] = (xs[c] - mu) * rstd * w[c] + bias[c];
    }
}

extern "C" void kernel_launch(void* const* d_in, const int* in_sizes, int n_in,
                              void* d_out, int out_size, void* d_ws, size_t ws_size,
                              hipStream_t stream) {
    const float* dec_inp  = (const float*)d_in[0];
    const float* r        = (const float*)d_in[1];
    const float* r_w_bias = (const float*)d_in[2];
    const float* r_r_bias = (const float*)d_in[3];
    const float* mems     = (const float*)d_in[4];
    // d_in[5] = dec_attn_mask (recomputed analytically, unused)
    const float* qkv_w    = (const float*)d_in[6];
    const float* r_w      = (const float*)d_in[7];
    const float* o_w      = (const float*)d_in[8];
    const float* ln1_w    = (const float*)d_in[9];
    const float* ln1_b    = (const float*)d_in[10];
    const float* ln2_w    = (const float*)d_in[11];
    const float* ln2_b    = (const float*)d_in[12];
    const float* ff_w1    = (const float*)d_in[13];
    const float* ff_b1    = (const float*)d_in[14];
    const float* ff_w2    = (const float*)d_in[15];
    const float* ff_b2    = (const float*)d_in[16];
    float* out = (float*)d_out;
    float* ws = (float*)d_ws;

    float* cat      = ws + OFF_CAT;
    float* w_heads  = ws + OFF_WH;
    float* r_head_k = ws + OFF_RHK;
    float* attn_vec = ws + OFF_AV;
    float* tmp      = ws + OFF_TMP;
    float* ln1_out  = ws + OFF_LN1;
    float* ff_hid   = ws + OFF_FFH;

    // cat = concat(mems, dec_inp) along position axis (both contiguous)
    const size_t half_bytes = (size_t)MLEN * BSZ * DM * sizeof(float);
    hipMemcpyAsync(cat, mems, half_bytes, hipMemcpyDeviceToDevice, stream);
    hipMemcpyAsync(cat + (size_t)MLEN * BSZ * DM, dec_inp, half_bytes,
                   hipMemcpyDeviceToDevice, stream);

    // w_heads = cat @ qkv_w : (8192, 3072, K=1024)
    gemm64<<<dim3(3 * NHD / 64, KLEN * BSZ / 64), 256, 0, stream>>>(
        cat, qkv_w, nullptr, w_heads, KLEN * BSZ, 3 * NHD, DM, 0);

    // r_head_k = r @ r_w : (2048, 1024, K=1024)
    gemm64<<<dim3(NHD / 64, KLEN / 64), 256, 0, stream>>>(
        r, r_w, nullptr, r_head_k, KLEN, NHD, DM, 0);

    // attention
    attn_kernel<<<dim3(QLEN, BSZ * NH), 256, 0, stream>>>(
        w_heads, r_head_k, r_w_bias, r_r_bias, attn_vec);

    // attn_out = attn_vec @ o_w : (4096, 1024, K=1024)
    gemm64<<<dim3(DM / 64, QLEN * BSZ / 64), 256, 0, stream>>>(
        attn_vec, o_w, nullptr, tmp, QLEN * BSZ, DM, NHD, 0);

    // ln1_out = LN(dec_inp + attn_out)
    add_ln_kernel<<<dim3(QLEN * BSZ), 256, 0, stream>>>(
        dec_inp, tmp, ln1_w, ln1_b, ln1_out);

    // ff_hid = relu(ln1_out @ ff_w1 + b1) : (4096, 4096, K=1024)
    gemm64<<<dim3(DI / 64, QLEN * BSZ / 64), 256, 0, stream>>>(
        ln1_out, ff_w1, ff_b1, ff_hid, QLEN * BSZ, DI, DM, 3);

    // tmp = ff_hid @ ff_w2 + b2 : (4096, 1024, K=4096)
    gemm64<<<dim3(DM / 64, QLEN * BSZ / 64), 256, 0, stream>>>(
        ff_hid, ff_w2, ff_b2, tmp, QLEN * BSZ, DM, DI, 1);

    // out = LN(ln1_out + tmp)
    add_ln_kernel<<<dim3(QLEN * BSZ), 256, 0, stream>>>(
        ln1_out, tmp, ln2_w, ln2_b, out);
}

// Round 2
// 3995.260 us; speedup vs baseline: 3.7532x; 3.7532x over previous
//
#include <hip/hip_runtime.h>
#include <hip/hip_bf16.h>
#include <math.h>

#define QLEN 1024
#define MLEN 1024
#define BSZ 4
#define KLEN 2048
#define NH 16
#define DH 64
#define DM 1024
#define DI 4096
#define NHD 1024
#define LN_EPS 1e-5f

// ---------------- workspace layout (floats) ----------------
static const size_t OFF_CAT = 0;
static const size_t OFF_WH  = 8388608;
static const size_t OFF_RHK = 33554432;
static const size_t OFF_AV  = 35651584;
static const size_t OFF_TMP = 39845888;
static const size_t OFF_LN1 = 44040192;
static const size_t OFF_FFH = 0; // ff hidden reuses cat/w_heads region (dead by then)

// ---------------- generic 64x64 tiled fp32 GEMM ----------------
__global__ __launch_bounds__(256) void gemm64(const float* __restrict__ A,
                                              const float* __restrict__ B,
                                              const float* __restrict__ bias,
                                              float* __restrict__ C,
                                              int M, int N, int K, int flags) {
    __shared__ float As[64][17];
    __shared__ float Bs[16][65];
    int t = threadIdx.x;
    int col0 = blockIdx.x * 64;
    int row0 = blockIdx.y * 64;
    int tx = t % 16, ty = t / 16;

    int la_row = t >> 2;
    int la_col = (t & 3) * 4;
    int lb_row = t >> 4;
    int lb_col = (t & 15) * 4;

    float acc[4][4] = {};

    for (int k0 = 0; k0 < K; k0 += 16) {
        float4 av = *(const float4*)&A[(size_t)(row0 + la_row) * K + k0 + la_col];
        As[la_row][la_col + 0] = av.x;
        As[la_row][la_col + 1] = av.y;
        As[la_row][la_col + 2] = av.z;
        As[la_row][la_col + 3] = av.w;
        float4 bv = *(const float4*)&B[(size_t)(k0 + lb_row) * N + col0 + lb_col];
        Bs[lb_row][lb_col + 0] = bv.x;
        Bs[lb_row][lb_col + 1] = bv.y;
        Bs[lb_row][lb_col + 2] = bv.z;
        Bs[lb_row][lb_col + 3] = bv.w;
        __syncthreads();
#pragma unroll
        for (int kk = 0; kk < 16; ++kk) {
            float a0 = As[ty * 4 + 0][kk];
            float a1 = As[ty * 4 + 1][kk];
            float a2 = As[ty * 4 + 2][kk];
            float a3 = As[ty * 4 + 3][kk];
            float b0 = Bs[kk][tx * 4 + 0];
            float b1 = Bs[kk][tx * 4 + 1];
            float b2 = Bs[kk][tx * 4 + 2];
            float b3 = Bs[kk][tx * 4 + 3];
            acc[0][0] += a0 * b0; acc[0][1] += a0 * b1; acc[0][2] += a0 * b2; acc[0][3] += a0 * b3;
            acc[1][0] += a1 * b0; acc[1][1] += a1 * b1; acc[1][2] += a1 * b2; acc[1][3] += a1 * b3;
            acc[2][0] += a2 * b0; acc[2][1] += a2 * b1; acc[2][2] += a2 * b2; acc[2][3] += a2 * b3;
            acc[3][0] += a3 * b0; acc[3][1] += a3 * b1; acc[3][2] += a3 * b2; acc[3][3] += a3 * b3;
        }
        __syncthreads();
    }
#pragma unroll
    for (int i = 0; i < 4; ++i) {
#pragma unroll
        for (int j = 0; j < 4; ++j) {
            int r = row0 + ty * 4 + i;
            int c = col0 + tx * 4 + j;
            float v = acc[i][j];
            if (flags & 1) v += bias[c];
            if (flags & 2) v = fmaxf(v, 0.0f);
            C[(size_t)r * N + c] = v;
        }
    }
}

// ---------------- fused flash attention ----------------
// Block: (32-query tile i0, batch b, head n). 256 threads.
// Thread t: query row iq = t>>3, lane-in-row c = t&7.
// Score phase: 4 j's per thread (j = c + 8*jj). PV phase: 8 d's (d = c*8+e).
// BD[i,j] = qbd_i . r_head_k[j - i + 1023] (rel_shift resolved; row index
// staged in sliding LDS window of 64 rows, base relbase = jt0 - i0 + 992).
__global__ __launch_bounds__(256) void flash_attn(const float* __restrict__ w_heads,
                                                  const float* __restrict__ r_head_k,
                                                  const float* __restrict__ r_w_bias,
                                                  const float* __restrict__ r_r_bias,
                                                  float* __restrict__ attn_vec) {
    const int i0 = blockIdx.x << 5;
    const int b = blockIdx.y >> 4;
    const int n = blockIdx.y & 15;
    const int t = threadIdx.x;
    const int nb = n * 64;

    __shared__ float qac[32][68];
    __shared__ float qbd[32][68];
    __shared__ float Ks[32][68];
    __shared__ float Vs[32][68];
    __shared__ float Rs[64][68];
    __shared__ float ps[32][36];

    // stage Q tile with both biases added
    for (int f = t; f < 512; f += 256) {
        int row = f >> 4, cw = (f & 15) << 2;
        float4 q = *(const float4*)&w_heads[((size_t)(MLEN + i0 + row) * BSZ + b) * 3072 + nb + cw];
        float4 wb = *(const float4*)&r_w_bias[nb + cw];
        float4 rb = *(const float4*)&r_r_bias[nb + cw];
        qac[row][cw + 0] = q.x + wb.x; qac[row][cw + 1] = q.y + wb.y;
        qac[row][cw + 2] = q.z + wb.z; qac[row][cw + 3] = q.w + wb.w;
        qbd[row][cw + 0] = q.x + rb.x; qbd[row][cw + 1] = q.y + rb.y;
        qbd[row][cw + 2] = q.z + rb.z; qbd[row][cw + 3] = q.w + rb.w;
    }

    const int iq = t >> 3;
    const int c = t & 7;
    const int i_glob = i0 + iq;
    const int jmax = i_glob + MLEN; // inclusive unmasked bound
    float m = -INFINITY, l = 0.f;
    float O[8] = {0.f, 0.f, 0.f, 0.f, 0.f, 0.f, 0.f, 0.f};

    const int ntiles = blockIdx.x + 33; // ceil((i0+31+MLEN+1)/32)
    for (int tile = 0; tile < ntiles; ++tile) {
        const int jt0 = tile << 5;
        __syncthreads(); // previous PV / Q-stage done before overwriting tiles

        // stage K and V tiles (32 x 64)
        for (int f = t; f < 512; f += 256) {
            int row = f >> 4, cw = (f & 15) << 2;
            size_t base = ((size_t)(jt0 + row) * BSZ + b) * 3072 + nb + cw;
            float4 kv = *(const float4*)&w_heads[base + NHD];
            float4 vv = *(const float4*)&w_heads[base + 2 * NHD];
            Ks[row][cw + 0] = kv.x; Ks[row][cw + 1] = kv.y;
            Ks[row][cw + 2] = kv.z; Ks[row][cw + 3] = kv.w;
            Vs[row][cw + 0] = vv.x; Vs[row][cw + 1] = vv.y;
            Vs[row][cw + 2] = vv.z; Vs[row][cw + 3] = vv.w;
        }
        // stage 64-row sliding window of r_head_k
        const int relbase = jt0 - i0 + 992;
        for (int f = t; f < 1024; f += 256) {
            int row = f >> 4, cw = (f & 15) << 2;
            int rel = relbase + row;
            rel = rel < 0 ? 0 : (rel > 2047 ? 2047 : rel);
            float4 rv = *(const float4*)&r_head_k[(size_t)rel * NHD + nb + cw];
            Rs[row][cw + 0] = rv.x; Rs[row][cw + 1] = rv.y;
            Rs[row][cw + 2] = rv.z; Rs[row][cw + 3] = rv.w;
        }
        __syncthreads();

        // ---- scores: s[jj] for j = jt0 + c + 8*jj ----
        float s0 = 0.f, s1 = 0.f, s2 = 0.f, s3 = 0.f;
#pragma unroll
        for (int d = 0; d < 64; d += 4) {
            float4 qa = *(const float4*)&qac[iq][d];
            float4 qb = *(const float4*)&qbd[iq][d];
            {
                float4 kv = *(const float4*)&Ks[c][d];
                float4 rv = *(const float4*)&Rs[c + 31 - iq][d];
                s0 += qa.x * kv.x + qa.y * kv.y + qa.z * kv.z + qa.w * kv.w
                    + qb.x * rv.x + qb.y * rv.y + qb.z * rv.z + qb.w * rv.w;
            }
            {
                float4 kv = *(const float4*)&Ks[c + 8][d];
                float4 rv = *(const float4*)&Rs[c + 8 + 31 - iq][d];
                s1 += qa.x * kv.x + qa.y * kv.y + qa.z * kv.z + qa.w * kv.w
                    + qb.x * rv.x + qb.y * rv.y + qb.z * rv.z + qb.w * rv.w;
            }
            {
                float4 kv = *(const float4*)&Ks[c + 16][d];
                float4 rv = *(const float4*)&Rs[c + 16 + 31 - iq][d];
                s2 += qa.x * kv.x + qa.y * kv.y + qa.z * kv.z + qa.w * kv.w
                    + qb.x * rv.x + qb.y * rv.y + qb.z * rv.z + qb.w * rv.w;
            }
            {
                float4 kv = *(const float4*)&Ks[c + 24][d];
                float4 rv = *(const float4*)&Rs[c + 24 + 31 - iq][d];
                s3 += qa.x * kv.x + qa.y * kv.y + qa.z * kv.z + qa.w * kv.w
                    + qb.x * rv.x + qb.y * rv.y + qb.z * rv.z + qb.w * rv.w;
            }
        }
        // mask + scale
        float sv[4] = {s0, s1, s2, s3};
        float tmax = -INFINITY;
#pragma unroll
        for (int jj = 0; jj < 4; ++jj) {
            int j = jt0 + c + (jj << 3);
            sv[jj] = (j <= jmax) ? sv[jj] * 0.125f : -INFINITY;
            tmax = fmaxf(tmax, sv[jj]);
        }
        // reduce max across the 8 lanes sharing iq
        tmax = fmaxf(tmax, __shfl_xor(tmax, 1));
        tmax = fmaxf(tmax, __shfl_xor(tmax, 2));
        tmax = fmaxf(tmax, __shfl_xor(tmax, 4));
        const float new_m = fmaxf(m, tmax);
        const float ef = __expf(m - new_m);
        float psum = 0.f;
#pragma unroll
        for (int jj = 0; jj < 4; ++jj) {
            float p = __expf(sv[jj] - new_m);
            ps[iq][c + (jj << 3)] = p;
            psum += p;
        }
        psum += __shfl_xor(psum, 1);
        psum += __shfl_xor(psum, 2);
        psum += __shfl_xor(psum, 4);
        l = l * ef + psum;
        m = new_m;

        // ---- PV: O[e] for d = c*8 + e (p written/read by same 8-lane group) ----
        const int d0 = c << 3;
#pragma unroll
        for (int e = 0; e < 8; ++e) O[e] *= ef;
#pragma unroll 4
        for (int j = 0; j < 32; ++j) {
            float p = ps[iq][j];
            float4 v0 = *(const float4*)&Vs[j][d0];
            float4 v1 = *(const float4*)&Vs[j][d0 + 4];
            O[0] += p * v0.x; O[1] += p * v0.y; O[2] += p * v0.z; O[3] += p * v0.w;
            O[4] += p * v1.x; O[5] += p * v1.y; O[6] += p * v1.z; O[7] += p * v1.w;
        }
    }

    const float inv = 1.0f / l;
    float4 o0 = {O[0] * inv, O[1] * inv, O[2] * inv, O[3] * inv};
    float4 o1 = {O[4] * inv, O[5] * inv, O[6] * inv, O[7] * inv};
    size_t ob = ((size_t)i_glob * BSZ + b) * NHD + nb + (c << 3);
    *(float4*)&attn_vec[ob] = o0;
    *(float4*)&attn_vec[ob + 4] = o1;
}

// ---------------- residual add + layernorm ----------------
__global__ __launch_bounds__(256) void add_ln_kernel(const float* __restrict__ a,
                                                     const float* __restrict__ b,
                                                     const float* __restrict__ w,
                                                     const float* __restrict__ bias,
                                                     float* __restrict__ out) {
    const int row = blockIdx.x;
    const int t = threadIdx.x;
    __shared__ float xs[DM];
    __shared__ float red[256];

    const float* ar = a + (size_t)row * DM;
    const float* br = b + (size_t)row * DM;

    float lsum = 0.f;
#pragma unroll
    for (int c = t; c < DM; c += 256) {
        float v = ar[c] + br[c];
        xs[c] = v;
        lsum += v;
    }
    red[t] = lsum;
    __syncthreads();
    for (int off = 128; off > 0; off >>= 1) {
        if (t < off) red[t] += red[t + off];
        __syncthreads();
    }
    const float mu = red[0] * (1.0f / DM);
    __syncthreads();

    float lvar = 0.f;
#pragma unroll
    for (int c = t; c < DM; c += 256) {
        float dv = xs[c] - mu;
        lvar += dv * dv;
    }
    red[t] = lvar;
    __syncthreads();
    for (int off = 128; off > 0; off >>= 1) {
        if (t < off) red[t] += red[t + off];
        __syncthreads();
    }
    const float rstd = rsqrtf(red[0] * (1.0f / DM) + LN_EPS);
    __syncthreads();

    float* orow = out + (size_t)row * DM;
#pragma unroll
    for (int c = t; c < DM; c += 256) {
        orow[c] = (xs[c] - mu) * rstd * w[c] + bias[c];
    }
}

extern "C" void kernel_launch(void* const* d_in, const int* in_sizes, int n_in,
                              void* d_out, int out_size, void* d_ws, size_t ws_size,
                              hipStream_t stream) {
    const float* dec_inp  = (const float*)d_in[0];
    const float* r        = (const float*)d_in[1];
    const float* r_w_bias = (const float*)d_in[2];
    const float* r_r_bias = (const float*)d_in[3];
    const float* mems     = (const float*)d_in[4];
    const float* qkv_w    = (const float*)d_in[6];
    const float* r_w      = (const float*)d_in[7];
    const float* o_w      = (const float*)d_in[8];
    const float* ln1_w    = (const float*)d_in[9];
    const float* ln1_b    = (const float*)d_in[10];
    const float* ln2_w    = (const float*)d_in[11];
    const float* ln2_b    = (const float*)d_in[12];
    const float* ff_w1    = (const float*)d_in[13];
    const float* ff_b1    = (const float*)d_in[14];
    const float* ff_w2    = (const float*)d_in[15];
    const float* ff_b2    = (const float*)d_in[16];
    float* out = (float*)d_out;
    float* ws = (float*)d_ws;

    float* cat      = ws + OFF_CAT;
    float* w_heads  = ws + OFF_WH;
    float* r_head_k = ws + OFF_RHK;
    float* attn_vec = ws + OFF_AV;
    float* tmp      = ws + OFF_TMP;
    float* ln1_out  = ws + OFF_LN1;
    float* ff_hid   = ws + OFF_FFH;

    const size_t half_bytes = (size_t)MLEN * BSZ * DM * sizeof(float);
    hipMemcpyAsync(cat, mems, half_bytes, hipMemcpyDeviceToDevice, stream);
    hipMemcpyAsync(cat + (size_t)MLEN * BSZ * DM, dec_inp, half_bytes,
                   hipMemcpyDeviceToDevice, stream);

    gemm64<<<dim3(3 * NHD / 64, KLEN * BSZ / 64), 256, 0, stream>>>(
        cat, qkv_w, nullptr, w_heads, KLEN * BSZ, 3 * NHD, DM, 0);

    gemm64<<<dim3(NHD / 64, KLEN / 64), 256, 0, stream>>>(
        r, r_w, nullptr, r_head_k, KLEN, NHD, DM, 0);

    flash_attn<<<dim3(QLEN / 32, BSZ * NH), 256, 0, stream>>>(
        w_heads, r_head_k, r_w_bias, r_r_bias, attn_vec);

    gemm64<<<dim3(DM / 64, QLEN * BSZ / 64), 256, 0, stream>>>(
        attn_vec, o_w, nullptr, tmp, QLEN * BSZ, DM, NHD, 0);

    add_ln_kernel<<<dim3(QLEN * BSZ), 256, 0, stream>>>(
        dec_inp, tmp, ln1_w, ln1_b, ln1_out);

    gemm64<<<dim3(DI / 64, QLEN * BSZ / 64), 256, 0, stream>>>(
        ln1_out, ff_w1, ff_b1, ff_hid, QLEN * BSZ, DI, DM, 3);

    gemm64<<<dim3(DM / 64, QLEN * BSZ / 64), 256, 0, stream>>>(
        ff_hid, ff_w2, ff_b2, tmp, QLEN * BSZ, DM, DI, 1);

    add_ln_kernel<<<dim3(QLEN * BSZ), 256, 0, stream>>>(
        ln1_out, tmp, ln2_w, ln2_b, out);
}

// Round 3
// 1639.352 us; speedup vs baseline: 9.1470x; 2.4371x over previous
//
#include <hip/hip_runtime.h>
#include <hip/hip_bf16.h>
#include <math.h>

#define QLEN 1024
#define MLEN 1024
#define BSZ 4
#define KLEN 2048
#define NH 16
#define DH 64
#define DM 1024
#define DI 4096
#define NHD 1024
#define LN_EPS 1e-5f

typedef short bf16x8 __attribute__((ext_vector_type(8)));
typedef float f32x4 __attribute__((ext_vector_type(4)));
typedef unsigned int uint4v __attribute__((ext_vector_type(4)));

__device__ __forceinline__ float bf2f(unsigned short u) {
    union { unsigned u32; float f; } x; x.u32 = ((unsigned)u) << 16; return x.f;
}
__device__ __forceinline__ unsigned short f2bf(float f) {
    __hip_bfloat16 h = __float2bfloat16(f);
    return *(unsigned short*)&h;
}

// ---------------- workspace layout (BYTE offsets) ----------------
static const size_t OFF_CATB  = 0;           //  16,777,216  cat bf16 [8192][1024]
static const size_t OFF_WHB   = 16777216;    //  50,331,648  w_heads bf16 [8192][3072]
static const size_t OFF_RB    = 67108864;    //   4,194,304  r bf16 [2048][1024]
static const size_t OFF_RHKB  = 71303168;    //   4,194,304  r_head_k bf16 [2048][1024]
static const size_t OFF_AVB   = 75497472;    //   8,388,608  attn_vec bf16 [4096][1024]
static const size_t OFF_TMP   = 83886080;    //  16,777,216  tmp fp32 [4096][1024]
static const size_t OFF_LN1F  = 100663296;   //  16,777,216  ln1 fp32
static const size_t OFF_LN1B  = 117440512;   //   8,388,608  ln1 bf16
static const size_t OFF_FFHB  = 125829120;   //  33,554,432  ff_hid bf16 [4096][4096]
static const size_t OFF_QKVWT = 159383552;   //   6,291,456  qkv_w^T bf16 [3072][1024]
static const size_t OFF_RWT   = 165675008;   //   2,097,152  r_w^T bf16 [1024][1024]
static const size_t OFF_OWT   = 167772160;   //   2,097,152  o_w^T bf16 [1024][1024]
static const size_t OFF_FFW1T = 169869312;   //   8,388,608  ff_w1^T bf16 [4096][1024]
static const size_t OFF_FFW2T = 178257920;   //   8,388,608  ff_w2^T bf16 [1024][4096]
// total 186,646,528 bytes

// ---------------- casts ----------------
__global__ __launch_bounds__(256) void cast_cat(const float* __restrict__ mems,
                                                const float* __restrict__ dec,
                                                unsigned short* __restrict__ out) {
    size_t i8 = ((size_t)blockIdx.x * 256 + threadIdx.x) * 8;
    const size_t half = (size_t)MLEN * BSZ * DM;
    const float* src = (i8 < half) ? (mems + i8) : (dec + (i8 - half));
    float4 v0 = *(const float4*)src;
    float4 v1 = *(const float4*)(src + 4);
    ushort4 o0 = {f2bf(v0.x), f2bf(v0.y), f2bf(v0.z), f2bf(v0.w)};
    ushort4 o1 = {f2bf(v1.x), f2bf(v1.y), f2bf(v1.z), f2bf(v1.w)};
    *(ushort4*)&out[i8] = o0;
    *(ushort4*)&out[i8 + 4] = o1;
}

__global__ __launch_bounds__(256) void cast_f32_bf16(const float* __restrict__ in,
                                                     unsigned short* __restrict__ out) {
    size_t i8 = ((size_t)blockIdx.x * 256 + threadIdx.x) * 8;
    float4 v0 = *(const float4*)(in + i8);
    float4 v1 = *(const float4*)(in + i8 + 4);
    ushort4 o0 = {f2bf(v0.x), f2bf(v0.y), f2bf(v0.z), f2bf(v0.w)};
    ushort4 o1 = {f2bf(v1.x), f2bf(v1.y), f2bf(v1.z), f2bf(v1.w)};
    *(ushort4*)&out[i8] = o0;
    *(ushort4*)&out[i8 + 4] = o1;
}

// in [K][N] fp32 -> out [N][K] bf16
__global__ __launch_bounds__(256) void transpose_cast(const float* __restrict__ in,
                                                      unsigned short* __restrict__ out,
                                                      int K, int N) {
    __shared__ float tile[32][33];
    const int t = threadIdx.x;
    const int n0 = blockIdx.x * 32;
    const int k0 = blockIdx.y * 32;
    const int r = t >> 3;
    const int c0 = (t & 7) << 2;
    float4 v = *(const float4*)&in[(size_t)(k0 + r) * N + n0 + c0];
    tile[r][c0 + 0] = v.x; tile[r][c0 + 1] = v.y;
    tile[r][c0 + 2] = v.z; tile[r][c0 + 3] = v.w;
    __syncthreads();
    ushort4 o = {f2bf(tile[c0 + 0][r]), f2bf(tile[c0 + 1][r]),
                 f2bf(tile[c0 + 2][r]), f2bf(tile[c0 + 3][r])};
    *(ushort4*)&out[(size_t)(n0 + r) * K + k0 + c0] = o;
}

// ---------------- bf16 MFMA GEMM ----------------
// C[M,N] = A[M,K] @ Bt[N,K]^T. flags: 1=+bias, 2=relu, 4=bf16 out (else fp32)
// 128x128 tile, 4 waves (2x2 of 64x64), BK=64, XOR-swizzled LDS.
__global__ __launch_bounds__(256) void gemm_bf16(const unsigned short* __restrict__ A,
                                                 const unsigned short* __restrict__ Bt,
                                                 const float* __restrict__ bias,
                                                 void* __restrict__ C,
                                                 int M, int N, int K, int flags) {
    __shared__ __align__(16) unsigned short As[128 * 64];
    __shared__ __align__(16) unsigned short Bs[128 * 64];

    const int tid = threadIdx.x;
    const int w = tid >> 6, l = tid & 63;
    const int wr = w >> 1, wc = w & 1;
    const int row0 = blockIdx.y * 128;
    const int col0 = blockIdx.x * 128;

    f32x4 acc[4][4] = {};

    uint4v ra[4], rb[4];
    // reg-stage tile kt=0
    {
        const int k0 = 0;
#pragma unroll
        for (int q = 0; q < 4; ++q) {
            int f = q * 256 + tid, r = f >> 3, c = f & 7;
            ra[q] = *(const uint4v*)&A[(size_t)(row0 + r) * K + k0 + c * 8];
            rb[q] = *(const uint4v*)&Bt[(size_t)(col0 + r) * K + k0 + c * 8];
        }
    }

    const int nt = K >> 6;
    for (int kt = 0; kt < nt; ++kt) {
        __syncthreads();
#pragma unroll
        for (int q = 0; q < 4; ++q) {
            int f = q * 256 + tid, r = f >> 3, c = f & 7;
            int sw = (c ^ (r & 7)) << 3;
            *(uint4v*)&As[r * 64 + sw] = ra[q];
            *(uint4v*)&Bs[r * 64 + sw] = rb[q];
        }
        __syncthreads();
        if (kt + 1 < nt) {
            const int k0 = (kt + 1) << 6;
#pragma unroll
            for (int q = 0; q < 4; ++q) {
                int f = q * 256 + tid, r = f >> 3, c = f & 7;
                ra[q] = *(const uint4v*)&A[(size_t)(row0 + r) * K + k0 + c * 8];
                rb[q] = *(const uint4v*)&Bt[(size_t)(col0 + r) * K + k0 + c * 8];
            }
        }
#pragma unroll
        for (int ks = 0; ks < 2; ++ks) {
            bf16x8 a[4], bfr[4];
#pragma unroll
            for (int m = 0; m < 4; ++m) {
                int arow = wr * 64 + m * 16 + (l & 15);
                int chunk = (ks * 4 + (l >> 4)) ^ (arow & 7);
                a[m] = *(const bf16x8*)&As[arow * 64 + chunk * 8];
            }
#pragma unroll
            for (int n = 0; n < 4; ++n) {
                int brow = wc * 64 + n * 16 + (l & 15);
                int chunk = (ks * 4 + (l >> 4)) ^ (brow & 7);
                bfr[n] = *(const bf16x8*)&Bs[brow * 64 + chunk * 8];
            }
#pragma unroll
            for (int m = 0; m < 4; ++m)
#pragma unroll
                for (int n = 0; n < 4; ++n)
                    acc[m][n] = __builtin_amdgcn_mfma_f32_16x16x32_bf16(a[m], bfr[n], acc[m][n], 0, 0, 0);
        }
    }

    // epilogue: C/D layout col=lane&15, row=(lane>>4)*4+reg
#pragma unroll
    for (int n = 0; n < 4; ++n) {
        const int ccol = col0 + wc * 64 + n * 16 + (l & 15);
        const float bv = (flags & 1) ? bias[ccol] : 0.0f;
#pragma unroll
        for (int m = 0; m < 4; ++m) {
            const int crow0 = row0 + wr * 64 + m * 16 + ((l >> 4) << 2);
#pragma unroll
            for (int reg = 0; reg < 4; ++reg) {
                float v = acc[m][n][reg] + bv;
                if (flags & 2) v = fmaxf(v, 0.0f);
                if (flags & 4)
                    ((unsigned short*)C)[(size_t)(crow0 + reg) * N + ccol] = f2bf(v);
                else
                    ((float*)C)[(size_t)(crow0 + reg) * N + ccol] = v;
            }
        }
    }
}

// ---------------- fused flash attention (bf16 inputs) ----------------
__global__ __launch_bounds__(256) void flash_attn(const unsigned short* __restrict__ wh,
                                                  const unsigned short* __restrict__ rhk,
                                                  const float* __restrict__ r_w_bias,
                                                  const float* __restrict__ r_r_bias,
                                                  unsigned short* __restrict__ attn_vec) {
    const int i0 = blockIdx.x << 5;
    const int b = blockIdx.y >> 4;
    const int n = blockIdx.y & 15;
    const int t = threadIdx.x;
    const int nb = n * 64;

    __shared__ float qac[32][68];
    __shared__ float qbd[32][68];
    __shared__ float Ks[32][68];
    __shared__ float Vs[32][68];
    __shared__ float Rs[64][68];
    __shared__ float ps[32][36];

    for (int f = t; f < 512; f += 256) {
        int row = f >> 4, cw = (f & 15) << 2;
        ushort4 q = *(const ushort4*)&wh[((size_t)(MLEN + i0 + row) * BSZ + b) * 3072 + nb + cw];
        float4 wb = *(const float4*)&r_w_bias[nb + cw];
        float4 rb = *(const float4*)&r_r_bias[nb + cw];
        qac[row][cw + 0] = bf2f(q.x) + wb.x; qac[row][cw + 1] = bf2f(q.y) + wb.y;
        qac[row][cw + 2] = bf2f(q.z) + wb.z; qac[row][cw + 3] = bf2f(q.w) + wb.w;
        qbd[row][cw + 0] = bf2f(q.x) + rb.x; qbd[row][cw + 1] = bf2f(q.y) + rb.y;
        qbd[row][cw + 2] = bf2f(q.z) + rb.z; qbd[row][cw + 3] = bf2f(q.w) + rb.w;
    }

    const int iq = t >> 3;
    const int c = t & 7;
    const int i_glob = i0 + iq;
    const int jmax = i_glob + MLEN;
    float m = -INFINITY, l = 0.f;
    float O[8] = {0.f, 0.f, 0.f, 0.f, 0.f, 0.f, 0.f, 0.f};

    const int ntiles = blockIdx.x + 33;
    for (int tile = 0; tile < ntiles; ++tile) {
        const int jt0 = tile << 5;
        __syncthreads();

        for (int f = t; f < 512; f += 256) {
            int row = f >> 4, cw = (f & 15) << 2;
            size_t base = ((size_t)(jt0 + row) * BSZ + b) * 3072 + nb + cw;
            ushort4 kv = *(const ushort4*)&wh[base + NHD];
            ushort4 vv = *(const ushort4*)&wh[base + 2 * NHD];
            Ks[row][cw + 0] = bf2f(kv.x); Ks[row][cw + 1] = bf2f(kv.y);
            Ks[row][cw + 2] = bf2f(kv.z); Ks[row][cw + 3] = bf2f(kv.w);
            Vs[row][cw + 0] = bf2f(vv.x); Vs[row][cw + 1] = bf2f(vv.y);
            Vs[row][cw + 2] = bf2f(vv.z); Vs[row][cw + 3] = bf2f(vv.w);
        }
        const int relbase = jt0 - i0 + 992;
        for (int f = t; f < 1024; f += 256) {
            int row = f >> 4, cw = (f & 15) << 2;
            int rel = relbase + row;
            rel = rel < 0 ? 0 : (rel > 2047 ? 2047 : rel);
            ushort4 rv = *(const ushort4*)&rhk[(size_t)rel * NHD + nb + cw];
            Rs[row][cw + 0] = bf2f(rv.x); Rs[row][cw + 1] = bf2f(rv.y);
            Rs[row][cw + 2] = bf2f(rv.z); Rs[row][cw + 3] = bf2f(rv.w);
        }
        __syncthreads();

        float s0 = 0.f, s1 = 0.f, s2 = 0.f, s3 = 0.f;
#pragma unroll
        for (int d = 0; d < 64; d += 4) {
            float4 qa = *(const float4*)&qac[iq][d];
            float4 qb = *(const float4*)&qbd[iq][d];
            {
                float4 kv = *(const float4*)&Ks[c][d];
                float4 rv = *(const float4*)&Rs[c + 31 - iq][d];
                s0 += qa.x * kv.x + qa.y * kv.y + qa.z * kv.z + qa.w * kv.w
                    + qb.x * rv.x + qb.y * rv.y + qb.z * rv.z + qb.w * rv.w;
            }
            {
                float4 kv = *(const float4*)&Ks[c + 8][d];
                float4 rv = *(const float4*)&Rs[c + 8 + 31 - iq][d];
                s1 += qa.x * kv.x + qa.y * kv.y + qa.z * kv.z + qa.w * kv.w
                    + qb.x * rv.x + qb.y * rv.y + qb.z * rv.z + qb.w * rv.w;
            }
            {
                float4 kv = *(const float4*)&Ks[c + 16][d];
                float4 rv = *(const float4*)&Rs[c + 16 + 31 - iq][d];
                s2 += qa.x * kv.x + qa.y * kv.y + qa.z * kv.z + qa.w * kv.w
                    + qb.x * rv.x + qb.y * rv.y + qb.z * rv.z + qb.w * rv.w;
            }
            {
                float4 kv = *(const float4*)&Ks[c + 24][d];
                float4 rv = *(const float4*)&Rs[c + 24 + 31 - iq][d];
                s3 += qa.x * kv.x + qa.y * kv.y + qa.z * kv.z + qa.w * kv.w
                    + qb.x * rv.x + qb.y * rv.y + qb.z * rv.z + qb.w * rv.w;
            }
        }
        float sv[4] = {s0, s1, s2, s3};
        float tmax = -INFINITY;
#pragma unroll
        for (int jj = 0; jj < 4; ++jj) {
            int j = jt0 + c + (jj << 3);
            sv[jj] = (j <= jmax) ? sv[jj] * 0.125f : -INFINITY;
            tmax = fmaxf(tmax, sv[jj]);
        }
        tmax = fmaxf(tmax, __shfl_xor(tmax, 1));
        tmax = fmaxf(tmax, __shfl_xor(tmax, 2));
        tmax = fmaxf(tmax, __shfl_xor(tmax, 4));
        const float new_m = fmaxf(m, tmax);
        const float ef = __expf(m - new_m);
        float psum = 0.f;
#pragma unroll
        for (int jj = 0; jj < 4; ++jj) {
            float p = __expf(sv[jj] - new_m);
            ps[iq][c + (jj << 3)] = p;
            psum += p;
        }
        psum += __shfl_xor(psum, 1);
        psum += __shfl_xor(psum, 2);
        psum += __shfl_xor(psum, 4);
        l = l * ef + psum;
        m = new_m;

        const int d0 = c << 3;
#pragma unroll
        for (int e = 0; e < 8; ++e) O[e] *= ef;
#pragma unroll 4
        for (int j = 0; j < 32; ++j) {
            float p = ps[iq][j];
            float4 v0 = *(const float4*)&Vs[j][d0];
            float4 v1 = *(const float4*)&Vs[j][d0 + 4];
            O[0] += p * v0.x; O[1] += p * v0.y; O[2] += p * v0.z; O[3] += p * v0.w;
            O[4] += p * v1.x; O[5] += p * v1.y; O[6] += p * v1.z; O[7] += p * v1.w;
        }
    }

    const float inv = 1.0f / l;
    ushort4 o0 = {f2bf(O[0] * inv), f2bf(O[1] * inv), f2bf(O[2] * inv), f2bf(O[3] * inv)};
    ushort4 o1 = {f2bf(O[4] * inv), f2bf(O[5] * inv), f2bf(O[6] * inv), f2bf(O[7] * inv)};
    size_t ob = ((size_t)i_glob * BSZ + b) * NHD + nb + (c << 3);
    *(ushort4*)&attn_vec[ob] = o0;
    *(ushort4*)&attn_vec[ob + 4] = o1;
}

// ---------------- residual add + layernorm (fp32 in, fp32 + optional bf16 out) ----------------
__global__ __launch_bounds__(256) void add_ln_kernel(const float* __restrict__ a,
                                                     const float* __restrict__ b,
                                                     const float* __restrict__ w,
                                                     const float* __restrict__ bias,
                                                     float* __restrict__ out,
                                                     unsigned short* __restrict__ out_bf) {
    const int row = blockIdx.x;
    const int t = threadIdx.x;
    __shared__ float xs[DM];
    __shared__ float red[256];

    const float* ar = a + (size_t)row * DM;
    const float* br = b + (size_t)row * DM;

    float lsum = 0.f;
#pragma unroll
    for (int c = t; c < DM; c += 256) {
        float v = ar[c] + br[c];
        xs[c] = v;
        lsum += v;
    }
    red[t] = lsum;
    __syncthreads();
    for (int off = 128; off > 0; off >>= 1) {
        if (t < off) red[t] += red[t + off];
        __syncthreads();
    }
    const float mu = red[0] * (1.0f / DM);
    __syncthreads();

    float lvar = 0.f;
#pragma unroll
    for (int c = t; c < DM; c += 256) {
        float dv = xs[c] - mu;
        lvar += dv * dv;
    }
    red[t] = lvar;
    __syncthreads();
    for (int off = 128; off > 0; off >>= 1) {
        if (t < off) red[t] += red[t + off];
        __syncthreads();
    }
    const float rstd = rsqrtf(red[0] * (1.0f / DM) + LN_EPS);
    __syncthreads();

    float* orow = out + (size_t)row * DM;
#pragma unroll
    for (int c = t; c < DM; c += 256) {
        float v = (xs[c] - mu) * rstd * w[c] + bias[c];
        orow[c] = v;
        if (out_bf) out_bf[(size_t)row * DM + c] = f2bf(v);
    }
}

extern "C" void kernel_launch(void* const* d_in, const int* in_sizes, int n_in,
                              void* d_out, int out_size, void* d_ws, size_t ws_size,
                              hipStream_t stream) {
    const float* dec_inp  = (const float*)d_in[0];
    const float* r        = (const float*)d_in[1];
    const float* r_w_bias = (const float*)d_in[2];
    const float* r_r_bias = (const float*)d_in[3];
    const float* mems     = (const float*)d_in[4];
    const float* qkv_w    = (const float*)d_in[6];
    const float* r_w      = (const float*)d_in[7];
    const float* o_w      = (const float*)d_in[8];
    const float* ln1_w    = (const float*)d_in[9];
    const float* ln1_b    = (const float*)d_in[10];
    const float* ln2_w    = (const float*)d_in[11];
    const float* ln2_b    = (const float*)d_in[12];
    const float* ff_w1    = (const float*)d_in[13];
    const float* ff_b1    = (const float*)d_in[14];
    const float* ff_w2    = (const float*)d_in[15];
    const float* ff_b2    = (const float*)d_in[16];
    float* out = (float*)d_out;
    char* ws = (char*)d_ws;

    unsigned short* catb  = (unsigned short*)(ws + OFF_CATB);
    unsigned short* whb   = (unsigned short*)(ws + OFF_WHB);
    unsigned short* rb    = (unsigned short*)(ws + OFF_RB);
    unsigned short* rhkb  = (unsigned short*)(ws + OFF_RHKB);
    unsigned short* avb   = (unsigned short*)(ws + OFF_AVB);
    float*          tmp   = (float*)(ws + OFF_TMP);
    float*          ln1f  = (float*)(ws + OFF_LN1F);
    unsigned short* ln1b  = (unsigned short*)(ws + OFF_LN1B);
    unsigned short* ffhb  = (unsigned short*)(ws + OFF_FFHB);
    unsigned short* qkvwT = (unsigned short*)(ws + OFF_QKVWT);
    unsigned short* rwT   = (unsigned short*)(ws + OFF_RWT);
    unsigned short* owT   = (unsigned short*)(ws + OFF_OWT);
    unsigned short* ffw1T = (unsigned short*)(ws + OFF_FFW1T);
    unsigned short* ffw2T = (unsigned short*)(ws + OFF_FFW2T);

    // casts & weight transposes
    cast_cat<<<dim3(4096), 256, 0, stream>>>(mems, dec_inp, catb);
    cast_f32_bf16<<<dim3(1024), 256, 0, stream>>>(r, rb);
    transpose_cast<<<dim3(96, 32), 256, 0, stream>>>(qkv_w, qkvwT, 1024, 3072);
    transpose_cast<<<dim3(32, 32), 256, 0, stream>>>(r_w, rwT, 1024, 1024);
    transpose_cast<<<dim3(32, 32), 256, 0, stream>>>(o_w, owT, 1024, 1024);
    transpose_cast<<<dim3(128, 32), 256, 0, stream>>>(ff_w1, ffw1T, 1024, 4096);
    transpose_cast<<<dim3(32, 128), 256, 0, stream>>>(ff_w2, ffw2T, 4096, 1024);

    // w_heads = cat @ qkv_w (bf16 out)
    gemm_bf16<<<dim3(24, 64), 256, 0, stream>>>(catb, qkvwT, nullptr, whb,
                                                KLEN * BSZ, 3 * NHD, DM, 4);
    // r_head_k = r @ r_w (bf16 out)
    gemm_bf16<<<dim3(8, 16), 256, 0, stream>>>(rb, rwT, nullptr, rhkb,
                                               KLEN, NHD, DM, 4);
    // attention
    flash_attn<<<dim3(QLEN / 32, BSZ * NH), 256, 0, stream>>>(
        whb, rhkb, r_w_bias, r_r_bias, avb);
    // attn_out = attn_vec @ o_w (fp32 out)
    gemm_bf16<<<dim3(8, 32), 256, 0, stream>>>(avb, owT, nullptr, tmp,
                                               QLEN * BSZ, DM, NHD, 0);
    // ln1
    add_ln_kernel<<<dim3(QLEN * BSZ), 256, 0, stream>>>(
        dec_inp, tmp, ln1_w, ln1_b, ln1f, ln1b);
    // ff_hid = relu(ln1 @ ff_w1 + b1) (bf16 out)
    gemm_bf16<<<dim3(32, 32), 256, 0, stream>>>(ln1b, ffw1T, ff_b1, ffhb,
                                                QLEN * BSZ, DI, DM, 1 | 2 | 4);
    // ff_out = ff_hid @ ff_w2 + b2 (fp32 out)
    gemm_bf16<<<dim3(8, 32), 256, 0, stream>>>(ffhb, ffw2T, ff_b2, tmp,
                                               QLEN * BSZ, DM, DI, 1);
    // ln2 -> out
    add_ln_kernel<<<dim3(QLEN * BSZ), 256, 0, stream>>>(
        ln1f, tmp, ln2_w, ln2_b, out, nullptr);
}

// Round 4
// 493.888 us; speedup vs baseline: 30.3613x; 3.3193x over previous
//
#include <hip/hip_runtime.h>
#include <hip/hip_bf16.h>
#include <math.h>

#define QLEN 1024
#define MLEN 1024
#define BSZ 4
#define KLEN 2048
#define NH 16
#define DH 64
#define DM 1024
#define DI 4096
#define NHD 1024
#define LN_EPS 1e-5f

typedef short bf16x8 __attribute__((ext_vector_type(8)));
typedef float f32x4 __attribute__((ext_vector_type(4)));
typedef unsigned int uint4v __attribute__((ext_vector_type(4)));

__device__ __forceinline__ float bf2f(unsigned short u) {
    union { unsigned u32; float f; } x; x.u32 = ((unsigned)u) << 16; return x.f;
}
__device__ __forceinline__ unsigned short f2bf(float f) {
    __hip_bfloat16 h = __float2bfloat16(f);
    return *(unsigned short*)&h;
}

// ---------------- workspace layout (BYTE offsets) ----------------
static const size_t OFF_CATB  = 0;           //  16,777,216  cat bf16 (dead after qkv gemm)
static const size_t OFF_VTG   = 0;           //  16,777,216  Vt_g bf16 [64 bn][64 d][2048 keys] (reuses CATB)
static const size_t OFF_WHB   = 16777216;    //  50,331,648  w_heads bf16 [8192][3072]
static const size_t OFF_RB    = 67108864;    //   4,194,304  r bf16 [2048][1024]
static const size_t OFF_RHKB  = 71303168;    //   4,194,304  r_head_k bf16 [2048][1024]
static const size_t OFF_AVB   = 75497472;    //   8,388,608  attn_vec bf16 [4096][1024]
static const size_t OFF_TMP   = 83886080;    //  16,777,216  tmp fp32 [4096][1024]
static const size_t OFF_LN1F  = 100663296;   //  16,777,216  ln1 fp32
static const size_t OFF_LN1B  = 117440512;   //   8,388,608  ln1 bf16
static const size_t OFF_FFHB  = 125829120;   //  33,554,432  ff_hid bf16 [4096][4096]
static const size_t OFF_QKVWT = 159383552;   //   6,291,456  qkv_w^T bf16 [3072][1024]
static const size_t OFF_RWT   = 165675008;   //   2,097,152  r_w^T bf16
static const size_t OFF_OWT   = 167772160;   //   2,097,152  o_w^T bf16
static const size_t OFF_FFW1T = 169869312;   //   8,388,608  ff_w1^T bf16
static const size_t OFF_FFW2T = 178257920;   //   8,388,608  ff_w2^T bf16
static const size_t OFF_BK    = 186646528;   //     524,288  bias_k fp32 [64 bn][2048]
static const size_t OFF_BR    = 187170816;   //     131,072  bias_r fp32 [16 n][2048]
// end 187,301,888 < 192,937,984 (round-0 proven budget)

// ---------------- casts ----------------
__global__ __launch_bounds__(256) void cast_cat(const float* __restrict__ mems,
                                                const float* __restrict__ dec,
                                                unsigned short* __restrict__ out) {
    size_t i8 = ((size_t)blockIdx.x * 256 + threadIdx.x) * 8;
    const size_t half = (size_t)MLEN * BSZ * DM;
    const float* src = (i8 < half) ? (mems + i8) : (dec + (i8 - half));
    float4 v0 = *(const float4*)src;
    float4 v1 = *(const float4*)(src + 4);
    ushort4 o0 = {f2bf(v0.x), f2bf(v0.y), f2bf(v0.z), f2bf(v0.w)};
    ushort4 o1 = {f2bf(v1.x), f2bf(v1.y), f2bf(v1.z), f2bf(v1.w)};
    *(ushort4*)&out[i8] = o0;
    *(ushort4*)&out[i8 + 4] = o1;
}

__global__ __launch_bounds__(256) void cast_f32_bf16(const float* __restrict__ in,
                                                     unsigned short* __restrict__ out) {
    size_t i8 = ((size_t)blockIdx.x * 256 + threadIdx.x) * 8;
    float4 v0 = *(const float4*)(in + i8);
    float4 v1 = *(const float4*)(in + i8 + 4);
    ushort4 o0 = {f2bf(v0.x), f2bf(v0.y), f2bf(v0.z), f2bf(v0.w)};
    ushort4 o1 = {f2bf(v1.x), f2bf(v1.y), f2bf(v1.z), f2bf(v1.w)};
    *(ushort4*)&out[i8] = o0;
    *(ushort4*)&out[i8 + 4] = o1;
}

// in [K][N] fp32 -> out [N][K] bf16
__global__ __launch_bounds__(256) void transpose_cast(const float* __restrict__ in,
                                                      unsigned short* __restrict__ out,
                                                      int K, int N) {
    __shared__ float tile[32][33];
    const int t = threadIdx.x;
    const int n0 = blockIdx.x * 32;
    const int k0 = blockIdx.y * 32;
    const int r = t >> 3;
    const int c0 = (t & 7) << 2;
    float4 v = *(const float4*)&in[(size_t)(k0 + r) * N + n0 + c0];
    tile[r][c0 + 0] = v.x; tile[r][c0 + 1] = v.y;
    tile[r][c0 + 2] = v.z; tile[r][c0 + 3] = v.w;
    __syncthreads();
    ushort4 o = {f2bf(tile[c0 + 0][r]), f2bf(tile[c0 + 1][r]),
                 f2bf(tile[c0 + 2][r]), f2bf(tile[c0 + 3][r])};
    *(ushort4*)&out[(size_t)(n0 + r) * K + k0 + c0] = o;
}

// ---------------- bf16 MFMA GEMM (unchanged, proven) ----------------
__global__ __launch_bounds__(256) void gemm_bf16(const unsigned short* __restrict__ A,
                                                 const unsigned short* __restrict__ Bt,
                                                 const float* __restrict__ bias,
                                                 void* __restrict__ C,
                                                 int M, int N, int K, int flags) {
    __shared__ __align__(16) unsigned short As[128 * 64];
    __shared__ __align__(16) unsigned short Bs[128 * 64];

    const int tid = threadIdx.x;
    const int w = tid >> 6, l = tid & 63;
    const int wr = w >> 1, wc = w & 1;
    const int row0 = blockIdx.y * 128;
    const int col0 = blockIdx.x * 128;

    f32x4 acc[4][4] = {};

    uint4v ra[4], rb[4];
    {
#pragma unroll
        for (int q = 0; q < 4; ++q) {
            int f = q * 256 + tid, r = f >> 3, c = f & 7;
            ra[q] = *(const uint4v*)&A[(size_t)(row0 + r) * K + c * 8];
            rb[q] = *(const uint4v*)&Bt[(size_t)(col0 + r) * K + c * 8];
        }
    }

    const int nt = K >> 6;
    for (int kt = 0; kt < nt; ++kt) {
        __syncthreads();
#pragma unroll
        for (int q = 0; q < 4; ++q) {
            int f = q * 256 + tid, r = f >> 3, c = f & 7;
            int sw = (c ^ (r & 7)) << 3;
            *(uint4v*)&As[r * 64 + sw] = ra[q];
            *(uint4v*)&Bs[r * 64 + sw] = rb[q];
        }
        __syncthreads();
        if (kt + 1 < nt) {
            const int k0 = (kt + 1) << 6;
#pragma unroll
            for (int q = 0; q < 4; ++q) {
                int f = q * 256 + tid, r = f >> 3, c = f & 7;
                ra[q] = *(const uint4v*)&A[(size_t)(row0 + r) * K + k0 + c * 8];
                rb[q] = *(const uint4v*)&Bt[(size_t)(col0 + r) * K + k0 + c * 8];
            }
        }
#pragma unroll
        for (int ks = 0; ks < 2; ++ks) {
            bf16x8 a[4], bfr[4];
#pragma unroll
            for (int m = 0; m < 4; ++m) {
                int arow = wr * 64 + m * 16 + (l & 15);
                int chunk = (ks * 4 + (l >> 4)) ^ (arow & 7);
                a[m] = *(const bf16x8*)&As[arow * 64 + chunk * 8];
            }
#pragma unroll
            for (int n = 0; n < 4; ++n) {
                int brow = wc * 64 + n * 16 + (l & 15);
                int chunk = (ks * 4 + (l >> 4)) ^ (brow & 7);
                bfr[n] = *(const bf16x8*)&Bs[brow * 64 + chunk * 8];
            }
#pragma unroll
            for (int m = 0; m < 4; ++m)
#pragma unroll
                for (int n = 0; n < 4; ++n)
                    acc[m][n] = __builtin_amdgcn_mfma_f32_16x16x32_bf16(a[m], bfr[n], acc[m][n], 0, 0, 0);
        }
    }

#pragma unroll
    for (int n = 0; n < 4; ++n) {
        const int ccol = col0 + wc * 64 + n * 16 + (l & 15);
        const float bv = (flags & 1) ? bias[ccol] : 0.0f;
#pragma unroll
        for (int m = 0; m < 4; ++m) {
            const int crow0 = row0 + wr * 64 + m * 16 + ((l >> 4) << 2);
#pragma unroll
            for (int reg = 0; reg < 4; ++reg) {
                float v = acc[m][n][reg] + bv;
                if (flags & 2) v = fmaxf(v, 0.0f);
                if (flags & 4)
                    ((unsigned short*)C)[(size_t)(crow0 + reg) * N + ccol] = f2bf(v);
                else
                    ((float*)C)[(size_t)(crow0 + reg) * N + ccol] = v;
            }
        }
    }
}

// ---------------- V transpose to global: Vt_g[bn][d][key] ----------------
__global__ __launch_bounds__(256) void vtrans(const unsigned short* __restrict__ whb,
                                              unsigned short* __restrict__ vtg) {
    __shared__ unsigned short tile[64][72];
    const int bn = blockIdx.y;
    const int b = bn >> 4, n = bn & 15, nb = n * 64;
    const int jt0 = blockIdx.x * 64;
    const int tid = threadIdx.x;
#pragma unroll
    for (int g = 0; g < 2; ++g) {
        int f = g * 256 + tid;
        int key = f >> 3, c = f & 7;
        uint4v v = *(const uint4v*)&whb[((size_t)(jt0 + key) * 4 + b) * 3072 + 2048 + nb + c * 8];
        *(uint4v*)&tile[key][c * 8] = v;
    }
    __syncthreads();
#pragma unroll
    for (int g = 0; g < 2; ++g) {
        int f = g * 256 + tid;
        int d = f >> 3, ck = f & 7;
        unsigned short tmp[8];
#pragma unroll
        for (int e = 0; e < 8; ++e) tmp[e] = tile[ck * 8 + e][d];
        *(uint4v*)&vtg[(size_t)bn * 131072 + (size_t)d * 2048 + jt0 + ck * 8] = *(uint4v*)tmp;
    }
}

// ---------------- rank-1 bias precompute ----------------
__global__ __launch_bounds__(256) void bias_kernel(const unsigned short* __restrict__ whb,
                                                   const unsigned short* __restrict__ rhkb,
                                                   const float* __restrict__ r_w_bias,
                                                   const float* __restrict__ r_r_bias,
                                                   float* __restrict__ bias_k,
                                                   float* __restrict__ bias_r) {
    int id = blockIdx.x * 256 + threadIdx.x;
    if (id < 64 * 2048) {
        int bn = id >> 11, j = id & 2047;
        int b = bn >> 4, n = bn & 15;
        const unsigned short* kp = &whb[((size_t)j * 4 + b) * 3072 + 1024 + n * 64];
        const float* wb = &r_w_bias[n * 64];
        float acc = 0.f;
#pragma unroll
        for (int d = 0; d < 64; ++d) acc += wb[d] * bf2f(kp[d]);
        bias_k[id] = acc;
    } else {
        int id2 = id - 64 * 2048;
        if (id2 < 16 * 2048) {
            int n = id2 >> 11, rel = id2 & 2047;
            const unsigned short* rp = &rhkb[(size_t)rel * 1024 + n * 64];
            const float* rb = &r_r_bias[n * 64];
            float acc = 0.f;
#pragma unroll
            for (int d = 0; d < 64; ++d) acc += rb[d] * bf2f(rp[d]);
            bias_r[id2] = acc;
        }
    }
}

// ---------------- MFMA flash attention ----------------
// Block: (64-q tile bx, bn). 4 waves; wave wq owns q rows [wq*16, wq*16+16).
// score(i,j) = [Q.K^T + bias_k(j) + Q.Rwin^T|shift + bias_r(rel)] * 0.125, causal-masked.
__global__ __launch_bounds__(256) void flash_attn_mfma(const unsigned short* __restrict__ whb,
                                                       const unsigned short* __restrict__ rhkb,
                                                       const unsigned short* __restrict__ vtg,
                                                       const float* __restrict__ bias_k,
                                                       const float* __restrict__ bias_r,
                                                       unsigned short* __restrict__ avb) {
    const int bx = blockIdx.x;
    const int bn = blockIdx.y;
    const int b = bn >> 4, n = bn & 15, nb = n * 64;
    const int i0 = bx << 6;
    const int tid = threadIdx.x;
    const int wq = tid >> 6;
    const int lane = tid & 63;
    const int rg = lane >> 4;
    const int lc = lane & 15;

    __shared__ __align__(16) unsigned short Ks[4096];   // [key][64d] swizzled
    __shared__ __align__(16) unsigned short Rs[8192];   // 2 slots x [64][64d] swizzled (circular rel window)
    __shared__ __align__(16) unsigned short Vt[4096];   // [d][64key] swizzled
    __shared__ __align__(16) unsigned short Ps[4096];   // per-wave [16 q][64 key] swizzled
    __shared__ float BDw[4 * 16 * 132];                 // per-wave [16 q][128 o], pitch 132
    __shared__ float bK[64];
    __shared__ float bR[128];

    // persistent Q fragments (A operand), loaded once from global
    bf16x8 qf[2];
    {
        const int qrow = MLEN + i0 + wq * 16 + lc;
        const unsigned short* qp = whb + ((size_t)qrow * 4 + b) * 3072 + nb + rg * 8;
        qf[0] = *(const bf16x8*)(qp);
        qf[1] = *(const bf16x8*)(qp + 32);
    }

    f32x4 Oacc[4] = {};
    float mrun[4] = {-INFINITY, -INFINITY, -INFINITY, -INFINITY};
    float lrun[4] = {0.f, 0.f, 0.f, 0.f};

    const int ntiles = bx + 17;
    for (int kt = 0; kt < ntiles; ++kt) {
        const int jt0 = kt << 6;
        const int relbase = jt0 - i0 + 960;  // window rel = relbase + w, w in [0,128)
        __syncthreads();
        // ---- stage K, Vt ----
#pragma unroll
        for (int g = 0; g < 2; ++g) {
            const int f = g * 256 + tid;
            const int row = f >> 3, c = f & 7;
            const uint4v kv = *(const uint4v*)&whb[((size_t)(jt0 + row) * 4 + b) * 3072 + 1024 + nb + c * 8];
            *(uint4v*)&Ks[row * 64 + ((c ^ (row & 7)) << 3)] = kv;
            const uint4v vv = *(const uint4v*)&vtg[(size_t)bn * 131072 + (size_t)row * 2048 + jt0 + c * 8];
            *(uint4v*)&Vt[row * 64 + ((c ^ (row & 7)) << 3)] = vv;
        }
        // ---- stage R window (circular: full 128 at kt=0, upper 64 after) ----
        {
            const int wlo = (kt == 0) ? 0 : 64;
            for (int w0 = wlo; w0 < 128; w0 += 32) {
                const int row = w0 + (tid >> 3);
                const int c = tid & 7;
                const int a = relbase + row;
                const int dst = ((a >> 6) & 1) * 4096 + (a & 63) * 64 + ((c ^ (a & 7)) << 3);
                const int aa = a > 2047 ? 2047 : a;
                const uint4v rv = *(const uint4v*)&rhkb[(size_t)aa * 1024 + nb + c * 8];
                *(uint4v*)&Rs[dst] = rv;
            }
        }
        // ---- stage rank-1 biases ----
        if (tid < 64) {
            bK[tid] = bias_k[(size_t)bn * 2048 + jt0 + tid];
        } else if (tid < 192) {
            const int w2 = tid - 64;
            int a = relbase + w2;
            if (a > 2047) a = 2047;
            bR[w2] = bias_r[n * 2048 + a];
        }
        __syncthreads();

        // ---- AC = Q.K^T ----
        f32x4 Sacc[4];
#pragma unroll
        for (int nf = 0; nf < 4; ++nf) {
            const int key = nf * 16 + lc;
            const int c7 = key & 7;
            const bf16x8 kf0 = *(const bf16x8*)&Ks[key * 64 + ((rg ^ c7) << 3)];
            const bf16x8 kf1 = *(const bf16x8*)&Ks[key * 64 + (((4 + rg) ^ c7) << 3)];
            f32x4 z = {0.f, 0.f, 0.f, 0.f};
            z = __builtin_amdgcn_mfma_f32_16x16x32_bf16(qf[0], kf0, z, 0, 0, 0);
            Sacc[nf] = __builtin_amdgcn_mfma_f32_16x16x32_bf16(qf[1], kf1, z, 0, 0, 0);
        }

        // ---- BD band = Q.Rwin^T, only the 5 needed 16-col groups for this wave ----
        float* bdw = &BDw[wq * 2112];  // 16*132
        const int nflo = 3 - wq;
        for (int nf8 = nflo; nf8 < nflo + 5; ++nf8) {
            const int a = relbase + nf8 * 16 + lc;
            const int rbase = ((a >> 6) & 1) * 4096 + (a & 63) * 64;
            const int c7 = a & 7;
            const bf16x8 rf0 = *(const bf16x8*)&Rs[rbase + ((rg ^ c7) << 3)];
            const bf16x8 rf1 = *(const bf16x8*)&Rs[rbase + (((4 + rg) ^ c7) << 3)];
            f32x4 bd = {0.f, 0.f, 0.f, 0.f};
            bd = __builtin_amdgcn_mfma_f32_16x16x32_bf16(qf[0], rf0, bd, 0, 0, 0);
            bd = __builtin_amdgcn_mfma_f32_16x16x32_bf16(qf[1], rf1, bd, 0, 0, 0);
            const int wcol = nf8 * 16 + lc;
#pragma unroll
            for (int r = 0; r < 4; ++r)
                bdw[(rg * 4 + r) * 132 + wcol] = bd[r];
        }

        // ---- scores + online softmax (per-wave, lane-group reductions) ----
        float sv[4][4];
        float tmax[4] = {-INFINITY, -INFINITY, -INFINITY, -INFINITY};
#pragma unroll
        for (int nf = 0; nf < 4; ++nf) {
            const int jl = nf * 16 + lc;
            const float bkv = bK[jl];
#pragma unroll
            for (int r = 0; r < 4; ++r) {
                const int qr = rg * 4 + r;
                const int o = 63 + jl - wq * 16 - qr;
                float s = Sacc[nf][r] + bkv + bdw[qr * 132 + o] + bR[o];
                s = (relbase + o <= 2047) ? s * 0.125f : -INFINITY;
                sv[nf][r] = s;
                tmax[r] = fmaxf(tmax[r], s);
            }
        }
        float ef[4];
#pragma unroll
        for (int r = 0; r < 4; ++r) {
            float tm = tmax[r];
            tm = fmaxf(tm, __shfl_xor(tm, 1));
            tm = fmaxf(tm, __shfl_xor(tm, 2));
            tm = fmaxf(tm, __shfl_xor(tm, 4));
            tm = fmaxf(tm, __shfl_xor(tm, 8));
            const float mn = fmaxf(mrun[r], tm);
            ef[r] = __expf(mrun[r] - mn);
            mrun[r] = mn;
        }
        float rsum[4] = {0.f, 0.f, 0.f, 0.f};
#pragma unroll
        for (int nf = 0; nf < 4; ++nf) {
            const int jl = nf * 16 + lc;
#pragma unroll
            for (int r = 0; r < 4; ++r) {
                const int qr = rg * 4 + r;
                const float p = __expf(sv[nf][r] - mrun[r]);
                rsum[r] += p;
                Ps[wq * 1024 + qr * 64 + (((jl >> 3) ^ (qr & 7)) << 3) + (jl & 7)] = f2bf(p);
            }
        }
#pragma unroll
        for (int r = 0; r < 4; ++r) {
            float rs = rsum[r];
            rs += __shfl_xor(rs, 1);
            rs += __shfl_xor(rs, 2);
            rs += __shfl_xor(rs, 4);
            rs += __shfl_xor(rs, 8);
            lrun[r] = lrun[r] * ef[r] + rs;
        }
#pragma unroll
        for (int nf = 0; nf < 4; ++nf)
#pragma unroll
            for (int r = 0; r < 4; ++r) Oacc[nf][r] *= ef[r];

        // ---- PV: O += P @ V ----
        {
            const int c7 = lc & 7;
            const bf16x8 pf0 = *(const bf16x8*)&Ps[wq * 1024 + lc * 64 + ((rg ^ c7) << 3)];
            const bf16x8 pf1 = *(const bf16x8*)&Ps[wq * 1024 + lc * 64 + (((4 + rg) ^ c7) << 3)];
#pragma unroll
            for (int nf = 0; nf < 4; ++nf) {
                const int d = nf * 16 + lc;
                const int d7 = d & 7;
                const bf16x8 vf0 = *(const bf16x8*)&Vt[d * 64 + ((rg ^ d7) << 3)];
                const bf16x8 vf1 = *(const bf16x8*)&Vt[d * 64 + (((4 + rg) ^ d7) << 3)];
                Oacc[nf] = __builtin_amdgcn_mfma_f32_16x16x32_bf16(pf0, vf0, Oacc[nf], 0, 0, 0);
                Oacc[nf] = __builtin_amdgcn_mfma_f32_16x16x32_bf16(pf1, vf1, Oacc[nf], 0, 0, 0);
            }
        }
    }

    // ---- epilogue ----
    float inv[4];
#pragma unroll
    for (int r = 0; r < 4; ++r) inv[r] = 1.0f / lrun[r];
#pragma unroll
    for (int nf = 0; nf < 4; ++nf) {
        const int d = nf * 16 + lc;
#pragma unroll
        for (int r = 0; r < 4; ++r) {
            const int iq = i0 + wq * 16 + rg * 4 + r;
            avb[((size_t)iq * 4 + b) * 1024 + nb + d] = f2bf(Oacc[nf][r] * inv[r]);
        }
    }
}

// ---------------- residual add + layernorm ----------------
__global__ __launch_bounds__(256) void add_ln_kernel(const float* __restrict__ a,
                                                     const float* __restrict__ b,
                                                     const float* __restrict__ w,
                                                     const float* __restrict__ bias,
                                                     float* __restrict__ out,
                                                     unsigned short* __restrict__ out_bf) {
    const int row = blockIdx.x;
    const int t = threadIdx.x;
    __shared__ float xs[DM];
    __shared__ float red[256];

    const float* ar = a + (size_t)row * DM;
    const float* br = b + (size_t)row * DM;

    float lsum = 0.f;
#pragma unroll
    for (int c = t; c < DM; c += 256) {
        float v = ar[c] + br[c];
        xs[c] = v;
        lsum += v;
    }
    red[t] = lsum;
    __syncthreads();
    for (int off = 128; off > 0; off >>= 1) {
        if (t < off) red[t] += red[t + off];
        __syncthreads();
    }
    const float mu = red[0] * (1.0f / DM);
    __syncthreads();

    float lvar = 0.f;
#pragma unroll
    for (int c = t; c < DM; c += 256) {
        float dv = xs[c] - mu;
        lvar += dv * dv;
    }
    red[t] = lvar;
    __syncthreads();
    for (int off = 128; off > 0; off >>= 1) {
        if (t < off) red[t] += red[t + off];
        __syncthreads();
    }
    const float rstd = rsqrtf(red[0] * (1.0f / DM) + LN_EPS);
    __syncthreads();

    float* orow = out + (size_t)row * DM;
#pragma unroll
    for (int c = t; c < DM; c += 256) {
        float v = (xs[c] - mu) * rstd * w[c] + bias[c];
        orow[c] = v;
        if (out_bf) out_bf[(size_t)row * DM + c] = f2bf(v);
    }
}

extern "C" void kernel_launch(void* const* d_in, const int* in_sizes, int n_in,
                              void* d_out, int out_size, void* d_ws, size_t ws_size,
                              hipStream_t stream) {
    const float* dec_inp  = (const float*)d_in[0];
    const float* r        = (const float*)d_in[1];
    const float* r_w_bias = (const float*)d_in[2];
    const float* r_r_bias = (const float*)d_in[3];
    const float* mems     = (const float*)d_in[4];
    const float* qkv_w    = (const float*)d_in[6];
    const float* r_w      = (const float*)d_in[7];
    const float* o_w      = (const float*)d_in[8];
    const float* ln1_w    = (const float*)d_in[9];
    const float* ln1_b    = (const float*)d_in[10];
    const float* ln2_w    = (const float*)d_in[11];
    const float* ln2_b    = (const float*)d_in[12];
    const float* ff_w1    = (const float*)d_in[13];
    const float* ff_b1    = (const float*)d_in[14];
    const float* ff_w2    = (const float*)d_in[15];
    const float* ff_b2    = (const float*)d_in[16];
    float* out = (float*)d_out;
    char* ws = (char*)d_ws;

    unsigned short* catb  = (unsigned short*)(ws + OFF_CATB);
    unsigned short* vtg   = (unsigned short*)(ws + OFF_VTG);
    unsigned short* whb   = (unsigned short*)(ws + OFF_WHB);
    unsigned short* rb    = (unsigned short*)(ws + OFF_RB);
    unsigned short* rhkb  = (unsigned short*)(ws + OFF_RHKB);
    unsigned short* avb   = (unsigned short*)(ws + OFF_AVB);
    float*          tmp   = (float*)(ws + OFF_TMP);
    float*          ln1f  = (float*)(ws + OFF_LN1F);
    unsigned short* ln1b  = (unsigned short*)(ws + OFF_LN1B);
    unsigned short* ffhb  = (unsigned short*)(ws + OFF_FFHB);
    unsigned short* qkvwT = (unsigned short*)(ws + OFF_QKVWT);
    unsigned short* rwT   = (unsigned short*)(ws + OFF_RWT);
    unsigned short* owT   = (unsigned short*)(ws + OFF_OWT);
    unsigned short* ffw1T = (unsigned short*)(ws + OFF_FFW1T);
    unsigned short* ffw2T = (unsigned short*)(ws + OFF_FFW2T);
    float*          bk    = (float*)(ws + OFF_BK);
    float*          brr   = (float*)(ws + OFF_BR);

    // casts & weight transposes
    cast_cat<<<dim3(4096), 256, 0, stream>>>(mems, dec_inp, catb);
    cast_f32_bf16<<<dim3(1024), 256, 0, stream>>>(r, rb);
    transpose_cast<<<dim3(96, 32), 256, 0, stream>>>(qkv_w, qkvwT, 1024, 3072);
    transpose_cast<<<dim3(32, 32), 256, 0, stream>>>(r_w, rwT, 1024, 1024);
    transpose_cast<<<dim3(32, 32), 256, 0, stream>>>(o_w, owT, 1024, 1024);
    transpose_cast<<<dim3(128, 32), 256, 0, stream>>>(ff_w1, ffw1T, 1024, 4096);
    transpose_cast<<<dim3(32, 128), 256, 0, stream>>>(ff_w2, ffw2T, 4096, 1024);

    // projections
    gemm_bf16<<<dim3(24, 64), 256, 0, stream>>>(catb, qkvwT, nullptr, whb,
                                                KLEN * BSZ, 3 * NHD, DM, 4);
    gemm_bf16<<<dim3(8, 16), 256, 0, stream>>>(rb, rwT, nullptr, rhkb,
                                               KLEN, NHD, DM, 4);

    // attention precomputes (catb dead now; vtg reuses it)
    vtrans<<<dim3(32, 64), 256, 0, stream>>>(whb, vtg);
    bias_kernel<<<dim3(640), 256, 0, stream>>>(whb, rhkb, r_w_bias, r_r_bias, bk, brr);

    // MFMA flash attention
    flash_attn_mfma<<<dim3(QLEN / 64, BSZ * NH), 256, 0, stream>>>(
        whb, rhkb, vtg, bk, brr, avb);

    // output projection + LN + FFN + LN
    gemm_bf16<<<dim3(8, 32), 256, 0, stream>>>(avb, owT, nullptr, tmp,
                                               QLEN * BSZ, DM, NHD, 0);
    add_ln_kernel<<<dim3(QLEN * BSZ), 256, 0, stream>>>(
        dec_inp, tmp, ln1_w, ln1_b, ln1f, ln1b);
    gemm_bf16<<<dim3(32, 32), 256, 0, stream>>>(ln1b, ffw1T, ff_b1, ffhb,
                                                QLEN * BSZ, DI, DM, 1 | 2 | 4);
    gemm_bf16<<<dim3(8, 32), 256, 0, stream>>>(ffhb, ffw2T, ff_b2, tmp,
                                               QLEN * BSZ, DM, DI, 1);
    add_ln_kernel<<<dim3(QLEN * BSZ), 256, 0, stream>>>(
        ln1f, tmp, ln2_w, ln2_b, out, nullptr);
}